// Round 1
// baseline (1495.999 us; speedup 1.0000x reference)
//
#include <hip/hip_runtime.h>
#include <math.h>

#define NEG_SLOPE 0.2f

__device__ __forceinline__ float lrelu(float x) { return x >= 0.f ? x : NEG_SLOPE * x; }

// ---------------------------------------------------------------------------
// Y[N x C] = X[N x 128] @ W[128 x C] + b     (C = 128 or 32)
// W staged in LDS; 64 rows per block; thread owns one output column.
// ---------------------------------------------------------------------------
template <int C>
__global__ __launch_bounds__(256) void xform_kernel(
    const float* __restrict__ X, const float* __restrict__ W,
    const float* __restrict__ b, float* __restrict__ Y, int n) {
  __shared__ float Wl[128 * C];
  for (int i = threadIdx.x * 4; i < 128 * C; i += 256 * 4) {
    *(float4*)(Wl + i) = *(const float4*)(W + i);
  }
  __syncthreads();
  const int c = threadIdx.x % C;
  const int rsub = threadIdx.x / C;
  const int row0 = blockIdx.x * 64;
  const int rowEnd = min(row0 + 64, n);
  const float bc = b[c];
  for (int row = row0 + rsub; row < rowEnd; row += 256 / C) {
    const float* xr = X + (size_t)row * 128;
    float acc = bc;
#pragma unroll 8
    for (int k = 0; k < 128; k += 4) {
      float4 xv = *(const float4*)(xr + k);
      acc += xv.x * Wl[(k + 0) * C + c];
      acc += xv.y * Wl[(k + 1) * C + c];
      acc += xv.z * Wl[(k + 2) * C + c];
      acc += xv.w * Wl[(k + 3) * C + c];
    }
    Y[(size_t)row * C + c] = acc;
  }
}

// ---------------------------------------------------------------------------
// Layer-1 edge logits: one wave per edge, lane l covers channels 2l, 2l+1.
// head h = lane/8 (16 channels per head). Stores exp(logit), accumulates denom.
// ---------------------------------------------------------------------------
__global__ __launch_bounds__(256) void edge1_logits(
    const int* __restrict__ ei, const float* __restrict__ xs,
    const float* __restrict__ xd, const float* __restrict__ att,
    float* __restrict__ expl, float* __restrict__ denom, int N, int E, int Etot) {
  const int wave = (int)((blockIdx.x * 256u + threadIdx.x) >> 6);
  const int lane = threadIdx.x & 63;
  if (wave >= Etot) return;
  int s, d;
  if (wave < E) { s = ei[wave]; d = ei[E + wave]; } else { s = d = wave - E; }
  s = min(max(s, 0), N - 1); d = min(max(d, 0), N - 1);
  float2 a = *(const float2*)(xs + (size_t)s * 128 + 2 * lane);
  float2 bb = *(const float2*)(xd + (size_t)d * 128 + 2 * lane);
  float2 at = *(const float2*)(att + 2 * lane);
  float p = lrelu(a.x + bb.x) * at.x + lrelu(a.y + bb.y) * at.y;
  p += __shfl_xor(p, 1);
  p += __shfl_xor(p, 2);
  p += __shfl_xor(p, 4);
  if ((lane & 7) == 0) {
    int h = lane >> 3;
    float ex = __expf(p);
    expl[(size_t)wave * 8 + h] = ex;
    atomicAdd(denom + (size_t)d * 8 + h, ex);
  }
}

// ---------------------------------------------------------------------------
// Layer-1 aggregation: out[dst] += alpha * xs[src]; one wave per edge.
// ---------------------------------------------------------------------------
__global__ __launch_bounds__(256) void edge1_agg(
    const int* __restrict__ ei, const float* __restrict__ xs,
    const float* __restrict__ expl, const float* __restrict__ denom,
    float* __restrict__ out, int N, int E, int Etot) {
  const int wave = (int)((blockIdx.x * 256u + threadIdx.x) >> 6);
  const int lane = threadIdx.x & 63;
  if (wave >= Etot) return;
  int s, d;
  if (wave < E) { s = ei[wave]; d = ei[E + wave]; } else { s = d = wave - E; }
  s = min(max(s, 0), N - 1); d = min(max(d, 0), N - 1);
  const int h = lane >> 3;
  float alpha = expl[(size_t)wave * 8 + h] / denom[(size_t)d * 8 + h];
  float2 m = *(const float2*)(xs + (size_t)s * 128 + 2 * lane);
  atomicAdd(out + (size_t)d * 128 + 2 * lane + 0, alpha * m.x);
  atomicAdd(out + (size_t)d * 128 + 2 * lane + 1, alpha * m.y);
}

// h = elu(h + bias)   (in place), row length 128
__global__ __launch_bounds__(256) void elu_bias(
    float* __restrict__ h, const float* __restrict__ bias, int total) {
  int i = blockIdx.x * 256 + threadIdx.x;
  if (i >= total) return;
  float v = h[i] + bias[i & 127];
  h[i] = v > 0.f ? v : __expf(v) - 1.f;
}

// ---------------------------------------------------------------------------
// Layer-2 edge logits: 32 channels, 1 head. Half-wave (32 lanes) per edge.
// ---------------------------------------------------------------------------
__global__ __launch_bounds__(256) void edge2_logits(
    const int* __restrict__ ei, const float* __restrict__ xs,
    const float* __restrict__ xd, const float* __restrict__ att,
    float* __restrict__ expl, float* __restrict__ denom, int N, int E, int Etot) {
  const int e = (int)((blockIdx.x * 256u + threadIdx.x) >> 5);
  const int c = threadIdx.x & 31;
  if (e >= Etot) return;
  int s, d;
  if (e < E) { s = ei[e]; d = ei[E + e]; } else { s = d = e - E; }
  s = min(max(s, 0), N - 1); d = min(max(d, 0), N - 1);
  float v = lrelu(xs[(size_t)s * 32 + c] + xd[(size_t)d * 32 + c]) * att[c];
  v += __shfl_xor(v, 1);
  v += __shfl_xor(v, 2);
  v += __shfl_xor(v, 4);
  v += __shfl_xor(v, 8);
  v += __shfl_xor(v, 16);
  if (c == 0) {
    float ex = __expf(v);
    expl[e] = ex;
    atomicAdd(denom + d, ex);
  }
}

__global__ __launch_bounds__(256) void edge2_agg(
    const int* __restrict__ ei, const float* __restrict__ xs,
    const float* __restrict__ expl, const float* __restrict__ denom,
    float* __restrict__ out, int N, int E, int Etot) {
  const int e = (int)((blockIdx.x * 256u + threadIdx.x) >> 5);
  const int c = threadIdx.x & 31;
  if (e >= Etot) return;
  int s, d;
  if (e < E) { s = ei[e]; d = ei[E + e]; } else { s = d = e - E; }
  s = min(max(s, 0), N - 1); d = min(max(d, 0), N - 1);
  float alpha = expl[e] / denom[d];
  atomicAdd(out + (size_t)d * 32 + c, alpha * xs[(size_t)s * 32 + c]);
}

// log_softmax over 32 classes; half-wave per node
__global__ __launch_bounds__(256) void lsm_kernel(
    const float* __restrict__ acc, const float* __restrict__ bias,
    float* __restrict__ out, int n) {
  const int i = (int)((blockIdx.x * 256u + threadIdx.x) >> 5);
  const int c = threadIdx.x & 31;
  if (i >= n) return;
  float v = acc[(size_t)i * 32 + c] + bias[c];
  float mx = v;
  mx = fmaxf(mx, __shfl_xor(mx, 1));
  mx = fmaxf(mx, __shfl_xor(mx, 2));
  mx = fmaxf(mx, __shfl_xor(mx, 4));
  mx = fmaxf(mx, __shfl_xor(mx, 8));
  mx = fmaxf(mx, __shfl_xor(mx, 16));
  float ex = __expf(v - mx);
  float sum = ex;
  sum += __shfl_xor(sum, 1);
  sum += __shfl_xor(sum, 2);
  sum += __shfl_xor(sum, 4);
  sum += __shfl_xor(sum, 8);
  sum += __shfl_xor(sum, 16);
  out[(size_t)i * 32 + c] = v - mx - __logf(sum);
}

extern "C" void kernel_launch(void* const* d_in, const int* in_sizes, int n_in,
                              void* d_out, int out_size, void* d_ws, size_t ws_size,
                              hipStream_t stream) {
  const float* x = (const float*)d_in[0];
  const int* ei = (const int*)d_in[1];
  const float* W1s = (const float*)d_in[2];
  const float* W1d = (const float*)d_in[3];
  const float* b1s = (const float*)d_in[4];
  const float* b1d = (const float*)d_in[5];
  const float* att1 = (const float*)d_in[6];
  const float* bias1 = (const float*)d_in[7];
  const float* W2s = (const float*)d_in[8];
  const float* W2d = (const float*)d_in[9];
  const float* b2s = (const float*)d_in[10];
  const float* b2d = (const float*)d_in[11];
  const float* att2 = (const float*)d_in[12];
  const float* bias2 = (const float*)d_in[13];
  float* out = (float*)d_out;

  const int N = in_sizes[0] / 128;
  const int E = in_sizes[1] / 2;
  const int Etot = E + N;

  float* ws = (float*)d_ws;
  float* xs1 = ws;    ws += (size_t)N * 128;
  float* xd1 = ws;    ws += (size_t)N * 128;
  float* expl1 = ws;  ws += (size_t)Etot * 8;
  float* denom1 = ws; ws += (size_t)N * 8;
  float* h1 = ws;     ws += (size_t)N * 128;   // accumulated, then elu'd in place
  float* xs2 = ws;    ws += (size_t)N * 32;
  float* xd2 = ws;    ws += (size_t)N * 32;
  float* expl2 = ws;  ws += (size_t)Etot;
  float* denom2 = ws; ws += (size_t)N;
  float* out2 = ws;   ws += (size_t)N * 32;

  hipMemsetAsync(denom1, 0, (size_t)N * 8 * sizeof(float), stream);
  hipMemsetAsync(h1, 0, (size_t)N * 128 * sizeof(float), stream);
  hipMemsetAsync(denom2, 0, (size_t)N * sizeof(float), stream);
  hipMemsetAsync(out2, 0, (size_t)N * 32 * sizeof(float), stream);

  const int xblocks = (N + 63) / 64;
  xform_kernel<128><<<xblocks, 256, 0, stream>>>(x, W1s, b1s, xs1, N);
  xform_kernel<128><<<xblocks, 256, 0, stream>>>(x, W1d, b1d, xd1, N);

  const int eb4 = (Etot + 3) / 4;   // 4 waves/block, 1 edge/wave
  edge1_logits<<<eb4, 256, 0, stream>>>(ei, xs1, xd1, att1, expl1, denom1, N, E, Etot);
  edge1_agg<<<eb4, 256, 0, stream>>>(ei, xs1, expl1, denom1, h1, N, E, Etot);

  const int total1 = N * 128;
  elu_bias<<<(total1 + 255) / 256, 256, 0, stream>>>(h1, bias1, total1);

  xform_kernel<32><<<xblocks, 256, 0, stream>>>(h1, W2s, b2s, xs2, N);
  xform_kernel<32><<<xblocks, 256, 0, stream>>>(h1, W2d, b2d, xd2, N);

  const int eb8 = (Etot + 7) / 8;   // 8 half-waves/block, 1 edge/half-wave
  edge2_logits<<<eb8, 256, 0, stream>>>(ei, xs2, xd2, att2, expl2, denom2, N, E, Etot);
  edge2_agg<<<eb8, 256, 0, stream>>>(ei, xs2, expl2, denom2, out2, N, E, Etot);

  lsm_kernel<<<(N + 7) / 8, 256, 0, stream>>>(out2, bias2, out, N);
}

// Round 2
// 797.913 us; speedup vs baseline: 1.8749x; 1.8749x over previous
//
#include <hip/hip_runtime.h>
#include <math.h>

#define NEG_SLOPE 0.2f

__device__ __forceinline__ float lrelu(float x) { return x >= 0.f ? x : NEG_SLOPE * x; }

// ---------------------------------------------------------------------------
// Y[N x C] = X[N x 128] @ W[128 x C] + b     (C = 128 or 32)
// ---------------------------------------------------------------------------
template <int C>
__global__ __launch_bounds__(256) void xform_kernel(
    const float* __restrict__ X, const float* __restrict__ W,
    const float* __restrict__ b, float* __restrict__ Y, int n) {
  __shared__ float Wl[128 * C];
  for (int i = threadIdx.x * 4; i < 128 * C; i += 256 * 4) {
    *(float4*)(Wl + i) = *(const float4*)(W + i);
  }
  __syncthreads();
  const int c = threadIdx.x % C;
  const int rsub = threadIdx.x / C;
  const int row0 = blockIdx.x * 64;
  const int rowEnd = min(row0 + 64, n);
  const float bc = b[c];
  for (int row = row0 + rsub; row < rowEnd; row += 256 / C) {
    const float* xr = X + (size_t)row * 128;
    float acc = bc;
#pragma unroll 8
    for (int k = 0; k < 128; k += 4) {
      float4 xv = *(const float4*)(xr + k);
      acc += xv.x * Wl[(k + 0) * C + c];
      acc += xv.y * Wl[(k + 1) * C + c];
      acc += xv.z * Wl[(k + 2) * C + c];
      acc += xv.w * Wl[(k + 3) * C + c];
    }
    Y[(size_t)row * C + c] = acc;
  }
}

// ---------------------------------------------------------------------------
// CSR build: histogram by dst, exclusive scan, scatter src into dst-order.
// Self-loops are NOT in the CSR; fused kernels add them inline.
// ---------------------------------------------------------------------------
__global__ __launch_bounds__(256) void hist_kernel(
    const int* __restrict__ ei, int* __restrict__ count, int N, int E) {
  int e = blockIdx.x * 256 + threadIdx.x;
  if (e >= E) return;
  int d = ei[E + e];
  d = min(max(d, 0), N - 1);
  atomicAdd(count + d, 1);
}

__global__ __launch_bounds__(1024) void scan_kernel(
    const int* __restrict__ count, int* __restrict__ row_ofs,
    int* __restrict__ wofs, int n) {
  __shared__ int partial[1024];
  const int tid = threadIdx.x;
  const int chunk = (n + 1023) / 1024;
  const int begin = min(tid * chunk, n);
  const int end = min(begin + chunk, n);
  int s = 0;
  for (int i = begin; i < end; i++) s += count[i];
  partial[tid] = s;
  __syncthreads();
  for (int off = 1; off < 1024; off <<= 1) {
    int t = (tid >= off) ? partial[tid - off] : 0;
    __syncthreads();
    partial[tid] += t;
    __syncthreads();
  }
  int running = partial[tid] - s;  // exclusive base of this chunk
  for (int i = begin; i < end; i++) {
    row_ofs[i] = running;
    wofs[i] = running;
    running += count[i];
  }
  if (tid == 1023) row_ofs[n] = partial[1023];
}

__global__ __launch_bounds__(256) void scatter_kernel(
    const int* __restrict__ ei, int* __restrict__ wofs,
    int* __restrict__ src_sorted, int N, int E) {
  int e = blockIdx.x * 256 + threadIdx.x;
  if (e >= E) return;
  int s = ei[e], d = ei[E + e];
  s = min(max(s, 0), N - 1);
  d = min(max(d, 0), N - 1);
  int pos = atomicAdd(wofs + d, 1);
  src_sorted[pos] = s;
}

// ---------------------------------------------------------------------------
// Layer-1 fused: per dst node (one wave), gather in-edges, online softmax-free
// accumulation (no max subtraction needed at these magnitudes):
//   out = (sum_e ex_e * msg_e) / (sum_e ex_e);  then +bias, ELU.
// lane l covers channels 2l,2l+1; head h = lane/8.
// ---------------------------------------------------------------------------
__global__ __launch_bounds__(256) void gat1_fused(
    const int* __restrict__ row_ofs, const int* __restrict__ src_sorted,
    const float* __restrict__ xs, const float* __restrict__ xd,
    const float* __restrict__ att, const float* __restrict__ bias,
    float* __restrict__ h1, int N) {
  const int node = (int)((blockIdx.x * 256u + threadIdx.x) >> 6);
  const int lane = threadIdx.x & 63;
  if (node >= N) return;
  const float2 at = *(const float2*)(att + 2 * lane);
  const float2 xdv = *(const float2*)(xd + (size_t)node * 128 + 2 * lane);
  float2 acc = make_float2(0.f, 0.f);
  float den = 0.f;
  const int b = row_ofs[node], eend = row_ofs[node + 1];
  // self-loop (always appended by reference)
  {
    float2 m = *(const float2*)(xs + (size_t)node * 128 + 2 * lane);
    float p = lrelu(m.x + xdv.x) * at.x + lrelu(m.y + xdv.y) * at.y;
    p += __shfl_xor(p, 1);
    p += __shfl_xor(p, 2);
    p += __shfl_xor(p, 4);
    float ex = __expf(p);
    den += ex;
    acc.x += ex * m.x;
    acc.y += ex * m.y;
  }
  int sNext = (b < eend) ? src_sorted[b] : 0;
  for (int e = b; e < eend; e++) {
    const int s = sNext;
    sNext = (e + 1 < eend) ? src_sorted[e + 1] : 0;
    float2 m = *(const float2*)(xs + (size_t)s * 128 + 2 * lane);
    float p = lrelu(m.x + xdv.x) * at.x + lrelu(m.y + xdv.y) * at.y;
    p += __shfl_xor(p, 1);
    p += __shfl_xor(p, 2);
    p += __shfl_xor(p, 4);
    float ex = __expf(p);
    den += ex;
    acc.x += ex * m.x;
    acc.y += ex * m.y;
  }
  const float inv = 1.f / den;
  float vx = acc.x * inv + bias[2 * lane];
  float vy = acc.y * inv + bias[2 * lane + 1];
  vx = vx > 0.f ? vx : __expf(vx) - 1.f;
  vy = vy > 0.f ? vy : __expf(vy) - 1.f;
  *(float2*)(h1 + (size_t)node * 128 + 2 * lane) = make_float2(vx, vy);
}

// ---------------------------------------------------------------------------
// Layer-2 fused: per dst node (half-wave, 32 ch, 1 head) + log_softmax.
// ---------------------------------------------------------------------------
__global__ __launch_bounds__(256) void gat2_fused(
    const int* __restrict__ row_ofs, const int* __restrict__ src_sorted,
    const float* __restrict__ xs, const float* __restrict__ xd,
    const float* __restrict__ att, const float* __restrict__ bias,
    float* __restrict__ out, int N) {
  const int node = (int)((blockIdx.x * 256u + threadIdx.x) >> 5);
  const int c = threadIdx.x & 31;
  if (node >= N) return;
  const float at = att[c];
  const float xdv = xd[(size_t)node * 32 + c];
  float acc = 0.f, den = 0.f;
  const int b = row_ofs[node], eend = row_ofs[node + 1];
  {
    float m = xs[(size_t)node * 32 + c];
    float p = lrelu(m + xdv) * at;
    p += __shfl_xor(p, 1);
    p += __shfl_xor(p, 2);
    p += __shfl_xor(p, 4);
    p += __shfl_xor(p, 8);
    p += __shfl_xor(p, 16);
    float ex = __expf(p);
    den += ex;
    acc += ex * m;
  }
  int sNext = (b < eend) ? src_sorted[b] : 0;
  for (int e = b; e < eend; e++) {
    const int s = sNext;
    sNext = (e + 1 < eend) ? src_sorted[e + 1] : 0;
    float m = xs[(size_t)s * 32 + c];
    float p = lrelu(m + xdv) * at;
    p += __shfl_xor(p, 1);
    p += __shfl_xor(p, 2);
    p += __shfl_xor(p, 4);
    p += __shfl_xor(p, 8);
    p += __shfl_xor(p, 16);
    float ex = __expf(p);
    den += ex;
    acc += ex * m;
  }
  float v = acc / den + bias[c];
  // log_softmax over the 32 channels
  float mx = v;
  mx = fmaxf(mx, __shfl_xor(mx, 1));
  mx = fmaxf(mx, __shfl_xor(mx, 2));
  mx = fmaxf(mx, __shfl_xor(mx, 4));
  mx = fmaxf(mx, __shfl_xor(mx, 8));
  mx = fmaxf(mx, __shfl_xor(mx, 16));
  float ex = __expf(v - mx);
  float sum = ex;
  sum += __shfl_xor(sum, 1);
  sum += __shfl_xor(sum, 2);
  sum += __shfl_xor(sum, 4);
  sum += __shfl_xor(sum, 8);
  sum += __shfl_xor(sum, 16);
  out[(size_t)node * 32 + c] = v - mx - __logf(sum);
}

extern "C" void kernel_launch(void* const* d_in, const int* in_sizes, int n_in,
                              void* d_out, int out_size, void* d_ws, size_t ws_size,
                              hipStream_t stream) {
  const float* x = (const float*)d_in[0];
  const int* ei = (const int*)d_in[1];
  const float* W1s = (const float*)d_in[2];
  const float* W1d = (const float*)d_in[3];
  const float* b1s = (const float*)d_in[4];
  const float* b1d = (const float*)d_in[5];
  const float* att1 = (const float*)d_in[6];
  const float* bias1 = (const float*)d_in[7];
  const float* W2s = (const float*)d_in[8];
  const float* W2d = (const float*)d_in[9];
  const float* b2s = (const float*)d_in[10];
  const float* b2d = (const float*)d_in[11];
  const float* att2 = (const float*)d_in[12];
  const float* bias2 = (const float*)d_in[13];
  float* out = (float*)d_out;

  const int N = in_sizes[0] / 128;
  const int E = in_sizes[1] / 2;

  float* ws = (float*)d_ws;
  float* xs1 = ws;  ws += (size_t)N * 128;
  float* xd1 = ws;  ws += (size_t)N * 128;
  float* h1 = ws;   ws += (size_t)N * 128;
  float* xs2 = ws;  ws += (size_t)N * 32;
  float* xd2 = ws;  ws += (size_t)N * 32;
  int* count = (int*)ws;       ws += N;
  int* row_ofs = (int*)ws;     ws += N + 1;
  int* wofs = (int*)ws;        ws += N + 1;
  int* src_sorted = (int*)ws;  ws += E;

  hipMemsetAsync(count, 0, (size_t)N * sizeof(int), stream);

  const int eblk = (E + 255) / 256;
  hist_kernel<<<eblk, 256, 0, stream>>>(ei, count, N, E);
  scan_kernel<<<1, 1024, 0, stream>>>(count, row_ofs, wofs, N);
  scatter_kernel<<<eblk, 256, 0, stream>>>(ei, wofs, src_sorted, N, E);

  const int xblocks = (N + 63) / 64;
  xform_kernel<128><<<xblocks, 256, 0, stream>>>(x, W1s, b1s, xs1, N);
  xform_kernel<128><<<xblocks, 256, 0, stream>>>(x, W1d, b1d, xd1, N);

  gat1_fused<<<(N + 3) / 4, 256, 0, stream>>>(row_ofs, src_sorted, xs1, xd1,
                                              att1, bias1, h1, N);

  xform_kernel<32><<<xblocks, 256, 0, stream>>>(h1, W2s, b2s, xs2, N);
  xform_kernel<32><<<xblocks, 256, 0, stream>>>(h1, W2d, b2d, xd2, N);

  gat2_fused<<<(N + 7) / 8, 256, 0, stream>>>(row_ofs, src_sorted, xs2, xd2,
                                              att2, bias2, out, N);
}